// Round 14
// baseline (9061.711 us; speedup 1.0000x reference)
//
#include <hip/hip_runtime.h>

#define T_LEN 200
#define HID   256
#define BATCH 1024
#define G3    768
#define ROWS  16
#define NTHREADS 512
#define WSZ   196608   // 768*256 elements per GRU weight matrix
#define NGRAN 25       // 200 / 8 time-granules

typedef __bf16  bf16x8 __attribute__((ext_vector_type(8)));
typedef float   f32x4  __attribute__((ext_vector_type(4)));

__device__ __forceinline__ unsigned short f2bf(float f) {
  union { float f; unsigned int u; } c; c.f = f;
  unsigned int u = c.u;
  u += 0x7FFFu + ((u >> 16) & 1u);
  return (unsigned short)(u >> 16);
}
__device__ __forceinline__ float bf2f(unsigned int u16v) {
  union { unsigned int u; float f; } c; c.u = u16v << 16; return c.f;
}
__device__ __forceinline__ float sigm(float x) { return 1.0f / (1.0f + __expf(-x)); }
__device__ __forceinline__ float tanh_f(float x) { return 1.0f - 2.0f / (__expf(2.0f * x) + 1.0f); }

__global__ void convert_weights(const float* __restrict__ a,
                                const float* __restrict__ b,
                                const float* __restrict__ c,
                                const float* __restrict__ d,
                                const float* __restrict__ e,
                                unsigned short* __restrict__ out) {
  int i = blockIdx.x * blockDim.x + threadIdx.x;
  const int total = 4 * WSZ + HID * HID;
  if (i >= total) return;
  float v;
  if      (i < 1 * WSZ) v = a[i];
  else if (i < 2 * WSZ) v = b[i - 1 * WSZ];
  else if (i < 3 * WSZ) v = c[i - 2 * WSZ];
  else if (i < 4 * WSZ) v = d[i - 3 * WSZ];
  else                  v = e[i - 4 * WSZ];
  out[i] = f2bf(v);
}

__device__ __forceinline__ bf16x8 lds_frag(const unsigned short* buf, int row, int k, int lq) {
  int chunk = (k << 2) + lq;
  int idx = row * HID + ((chunk ^ (row & 7)) << 3);
  return *reinterpret_cast<const bf16x8*>(buf + idx);
}
__device__ __forceinline__ bf16x8 gw_frag(const unsigned short* __restrict__ W, int wrow, int kof) {
  return *reinterpret_cast<const bf16x8*>(W + (size_t)wrow * HID + kof);
}
__device__ __forceinline__ uint2 pack4(f32x4 v) {
  uint2 r;
  r.x = (unsigned int)f2bf(v[0]) | ((unsigned int)f2bf(v[1]) << 16);
  r.y = (unsigned int)f2bf(v[2]) | ((unsigned int)f2bf(v[3]) << 16);
  return r;
}

// ---- cross-XCD coherent access ----
// LOADS: compiler-generated system-scope relaxed atomics (sc0 sc1) -- register-
// tracked (R13's asm-load + deferred-waitcnt read pending registers: miscompile).
__device__ __forceinline__ uint2 ld_u2_sys(const unsigned short* p) {
  unsigned long long v = __hip_atomic_load(
      reinterpret_cast<const unsigned long long*>(p),
      __ATOMIC_RELAXED, __HIP_MEMORY_SCOPE_SYSTEM);
  uint2 r; r.x = (unsigned int)v; r.y = (unsigned int)(v >> 32);
  return r;
}
// STORES: asm with sc0 sc1 (safe: operands read at issue; flag_set drains vmcnt)
__device__ __forceinline__ void st_u2_coh(unsigned short* p, uint2 v) {
  asm volatile("global_store_dwordx2 %0, %1, off sc0 sc1" :: "v"(p), "v"(v) : "memory");
}
__device__ __forceinline__ void st_sh_coh(unsigned short* p, unsigned int v) {
  asm volatile("global_store_short %0, %1, off sc0 sc1" :: "v"(p), "v"(v) : "memory");
}

__device__ __forceinline__ void flag_wait(int* f, int tid) {
  if (tid == 0) {
    while (!__hip_atomic_load(f, __ATOMIC_ACQUIRE, __HIP_MEMORY_SCOPE_AGENT))
      __builtin_amdgcn_s_sleep(2);
  }
  __syncthreads();
}
__device__ __forceinline__ void flag_set(int* f, int tid) {
  asm volatile("s_waitcnt vmcnt(0)" ::: "memory");
  __syncthreads();
  if (tid == 0) __hip_atomic_store(f, 1, __ATOMIC_RELEASE, __HIP_MEMORY_SCOPE_AGENT);
}

// ---- xp GEMM granule: As(LDS 128x256) @ W^T -> xpT granule (coherent stores) ----
__device__ __forceinline__ void xp_mfma_store(
    const unsigned short* As, const unsigned short* __restrict__ W,
    unsigned short* __restrict__ xpT, int bt, int t0, int w, int lr, int lq)
{
  const int colbase = w * 96;
  #pragma unroll 1
  for (int mt = 0; mt < 8; ++mt) {
    bf16x8 a[8];
    #pragma unroll
    for (int k = 0; k < 8; ++k) a[k] = lds_frag(As, mt * 16 + lr, k, lq);
    unsigned short* xprow = xpT + ((size_t)(t0 + mt) * 64 + bt) * (G3 * 16);
    #pragma unroll
    for (int np = 0; np < 3; ++np) {
      const int c0 = colbase + np * 32;
      f32x4 acc0 = {0,0,0,0}, acc1 = {0,0,0,0};
      #pragma unroll
      for (int k = 0; k < 8; ++k) {
        const int kof = k * 32 + lq * 8;
        bf16x8 b0 = gw_frag(W, c0 + lr,      kof);
        bf16x8 b1 = gw_frag(W, c0 + 16 + lr, kof);
        acc0 = __builtin_amdgcn_mfma_f32_16x16x32_bf16(a[k], b0, acc0, 0, 0, 0);
        acc1 = __builtin_amdgcn_mfma_f32_16x16x32_bf16(a[k], b1, acc1, 0, 0, 0);
      }
      st_u2_coh(xprow + (c0 + lr)      * 16 + lq * 4, pack4(acc0));
      st_u2_coh(xprow + (c0 + 16 + lr) * 16 + lq * 4, pack4(acc1));
    }
  }
}

// ---- stage B: xp0 (emb gather) granules, then xp1 (h0 @ Wih1^T) granules ----
__device__ __forceinline__ void role_b(
    const int* __restrict__ ids, const float* __restrict__ emb,
    const unsigned short* __restrict__ Wih0, const unsigned short* __restrict__ Wih1,
    unsigned short* __restrict__ xpT, const unsigned short* __restrict__ hbuf,
    int* flagZ, int* flagA, int* flagB,
    unsigned short* As, int bt, int tid)
{
  const int w = tid >> 6, lane = tid & 63, lr = lane & 15, lq = lane >> 4;
  const int r0 = bt * 16;

  for (int gt = 0; gt < NGRAN; ++gt) {            // phase 1: xp0
    const int t0 = gt * 8;
    for (int idx = tid; idx < 128 * 32; idx += NTHREADS) {
      int row = idx >> 5, cc = idx & 31;
      int bloc = row & 15, tloc = row >> 4;
      int sidx = row * HID + ((cc ^ (row & 7)) << 3);
      int rid = ids[(r0 + bloc) * T_LEN + t0 + tloc];
      const f32x4* src = reinterpret_cast<const f32x4*>(emb + (size_t)rid * HID + cc * 8);
      f32x4 v0 = src[0], v1 = src[1];
      uint4 pk;
      pk.x = (unsigned int)f2bf(v0[0]) | ((unsigned int)f2bf(v0[1]) << 16);
      pk.y = (unsigned int)f2bf(v0[2]) | ((unsigned int)f2bf(v0[3]) << 16);
      pk.z = (unsigned int)f2bf(v1[0]) | ((unsigned int)f2bf(v1[1]) << 16);
      pk.w = (unsigned int)f2bf(v1[2]) | ((unsigned int)f2bf(v1[3]) << 16);
      *reinterpret_cast<uint4*>(&As[sidx]) = pk;
    }
    __syncthreads();
    xp_mfma_store(As, Wih0, xpT, bt, t0, w, lr, lq);
    flag_set(flagZ + gt, tid);                    // also fences As for next fill
  }

  for (int gt = 0; gt < NGRAN; ++gt) {            // phase 2: xp1
    flag_wait(flagA + gt, tid);
    for (int idx = tid; idx < 128 * 32; idx += NTHREADS) {
      int row = idx >> 5, cc = idx & 31;
      int bloc = row & 15, tloc = row >> 4;
      int sidx = row * HID + ((cc ^ (row & 7)) << 3);
      const unsigned short* hs = hbuf + ((size_t)(gt * 8 + tloc) * 64 + bt) * (ROWS * HID)
                                      + bloc * HID + ((cc ^ (bloc & 7)) << 3);
      uint2 v0 = ld_u2_sys(hs);
      uint2 v1 = ld_u2_sys(hs + 4);
      uint4 v; v.x = v0.x; v.y = v0.y; v.z = v1.x; v.w = v1.y;
      *reinterpret_cast<uint4*>(&As[sidx]) = v;
    }
    __syncthreads();
    xp_mfma_store(As, Wih1, xpT, bt, gt * 8, w, lr, lq);
    flag_set(flagB + gt, tid);
  }
}

// ---- stages A/C: recurrent GRU layer, granule-gated, coherent I/O ----
__device__ __forceinline__ void role_rec(
    const unsigned short* __restrict__ xpT,
    const unsigned short* __restrict__ Whh,
    unsigned short* __restrict__ hbuf,
    int* inflag, int* outflag,
    unsigned short* smem, int bt, int tid)
{
  const int w = tid >> 6, lane = tid & 63, lr = lane & 15, lq = lane >> 4;
  const int c0 = w * 32;
  unsigned short* hb = smem;                      // [2][ROWS*HID]

  bf16x8 wf[2][3][8];
  #pragma unroll
  for (int j = 0; j < 2; ++j)
    #pragma unroll
    for (int g = 0; g < 3; ++g)
      #pragma unroll
      for (int k = 0; k < 8; ++k)
        wf[j][g][k] = gw_frag(Whh, g * 256 + c0 + j * 16 + lr, k * 32 + lq * 8);

  for (int i = tid; i < 2 * ROWS * HID; i += NTHREADS) hb[i] = 0;
  f32x4 hreg[2] = {{0,0,0,0},{0,0,0,0}};
  const int bj0 = (c0 + lr) * 16 + lq * 4;
  const size_t slabstep = (size_t)64 * G3 * 16;
  __syncthreads();

  int cur = 0;
  uint2 pz[2][3];
  #pragma unroll 1
  for (int gt = 0; gt < NGRAN; ++gt) {
    flag_wait(inflag + gt, tid);
    const unsigned short* slab = xpT + ((size_t)(gt * 8) * 64 + bt) * (G3 * 16);
    #pragma unroll
    for (int g = 0; g < 3; ++g) {
      pz[0][g] = ld_u2_sys(slab + g * 4096 + bj0);
      pz[1][g] = ld_u2_sys(slab + g * 4096 + bj0 + 256);
    }
    #pragma unroll 1
    for (int s = 0; s < 8; ++s) {
      const int t = gt * 8 + s;

      f32x4 acc[2][3];
      uint2 xn0 = pz[0][2], xn1 = pz[1][2];
      #pragma unroll
      for (int j = 0; j < 2; ++j) {
        #pragma unroll
        for (int g = 0; g < 2; ++g) {
          uint2 p = pz[j][g];
          f32x4 v;
          v[0] = bf2f(p.x & 0xffffu); v[1] = bf2f(p.x >> 16);
          v[2] = bf2f(p.y & 0xffffu); v[3] = bf2f(p.y >> 16);
          acc[j][g] = v;
        }
        f32x4 z4 = {0,0,0,0};
        acc[j][2] = z4;
      }
      if (s < 7) {   // prefetch next step (lands under MFMA+gates; barrier has no vmcnt drain)
        const unsigned short* slab2 = slab + slabstep;
        #pragma unroll
        for (int g = 0; g < 3; ++g) {
          pz[0][g] = ld_u2_sys(slab2 + g * 4096 + bj0);
          pz[1][g] = ld_u2_sys(slab2 + g * 4096 + bj0 + 256);
        }
      }
      asm volatile("s_waitcnt lgkmcnt(0)\ns_barrier" ::: "memory");

      const unsigned short* hbc = hb + cur * (ROWS * HID);
      #pragma unroll
      for (int k = 0; k < 8; ++k) {
        bf16x8 a = lds_frag(hbc, lr, k, lq);
        #pragma unroll
        for (int j = 0; j < 2; ++j) {
          acc[j][0] = __builtin_amdgcn_mfma_f32_16x16x32_bf16(a, wf[j][0][k], acc[j][0], 0, 0, 0);
          acc[j][1] = __builtin_amdgcn_mfma_f32_16x16x32_bf16(a, wf[j][1][k], acc[j][1], 0, 0, 0);
          acc[j][2] = __builtin_amdgcn_mfma_f32_16x16x32_bf16(a, wf[j][2][k], acc[j][2], 0, 0, 0);
        }
      }

      unsigned short* hbn = hb + (cur ^ 1) * (ROWS * HID);
      unsigned short* hslab = hbuf + ((size_t)t * 64 + bt) * (ROWS * HID);
      #pragma unroll
      for (int j = 0; j < 2; ++j) {
        uint2 xn = j ? xn1 : xn0;
        float xnv[4];
        xnv[0] = bf2f(xn.x & 0xffffu); xnv[1] = bf2f(xn.x >> 16);
        xnv[2] = bf2f(xn.y & 0xffffu); xnv[3] = bf2f(xn.y >> 16);
        #pragma unroll
        for (int q = 0; q < 4; ++q) {
          float r = sigm(acc[j][0][q]);
          float z = sigm(acc[j][1][q]);
          float n = tanh_f(xnv[q] + r * acc[j][2][q]);
          float hnew = fmaf(z, hreg[j][q] - n, n);
          hreg[j][q] = hnew;
          unsigned short h16 = f2bf(hnew);
          int m = lq * 4 + q;
          int c = c0 + j * 16 + lr;
          int off = m * HID + (((c >> 3) ^ (m & 7)) << 3) + (c & 7);
          hbn[off] = h16;
          st_sh_coh(hslab + off, (unsigned int)h16);
        }
      }
      slab += slabstep;
      cur ^= 1;
    }
    flag_set(outflag + gt, tid);
  }
}

// ---- stage D: dense epilogue per granule ----
__device__ __forceinline__ void role_d(
    const unsigned short* __restrict__ hbuf,
    const unsigned short* __restrict__ Wd, const float* __restrict__ db,
    float* __restrict__ out, int* flagC,
    unsigned short* As, int bt, int tid)
{
  const int w = tid >> 6, lane = tid & 63, lr = lane & 15, lq = lane >> 4;
  const int r0 = bt * 16;
  const int c0 = w * 32;
  const float b0v = db[c0 + lr];
  const float b1v = db[c0 + 16 + lr];

  for (int gt = 0; gt < NGRAN; ++gt) {
    flag_wait(flagC + gt, tid);
    for (int idx = tid; idx < 128 * 32; idx += NTHREADS) {
      int row = idx >> 5, cc = idx & 31;
      int bloc = row & 15, tloc = row >> 4;
      int sidx = row * HID + ((cc ^ (row & 7)) << 3);
      const unsigned short* hs = hbuf + ((size_t)(gt * 8 + tloc) * 64 + bt) * (ROWS * HID)
                                      + bloc * HID + ((cc ^ (bloc & 7)) << 3);
      uint2 v0 = ld_u2_sys(hs);
      uint2 v1 = ld_u2_sys(hs + 4);
      uint4 v; v.x = v0.x; v.y = v0.y; v.z = v1.x; v.w = v1.y;
      *reinterpret_cast<uint4*>(&As[sidx]) = v;
    }
    __syncthreads();
    #pragma unroll 1
    for (int mt = 0; mt < 8; ++mt) {
      bf16x8 a[8];
      #pragma unroll
      for (int k = 0; k < 8; ++k) a[k] = lds_frag(As, mt * 16 + lr, k, lq);
      f32x4 acc0 = {0,0,0,0}, acc1 = {0,0,0,0};
      #pragma unroll
      for (int k = 0; k < 8; ++k) {
        const int kof = k * 32 + lq * 8;
        bf16x8 b0 = gw_frag(Wd, c0 + lr,      kof);
        bf16x8 b1 = gw_frag(Wd, c0 + 16 + lr, kof);
        acc0 = __builtin_amdgcn_mfma_f32_16x16x32_bf16(a[k], b0, acc0, 0, 0, 0);
        acc1 = __builtin_amdgcn_mfma_f32_16x16x32_bf16(a[k], b1, acc1, 0, 0, 0);
      }
      const int t = gt * 8 + mt;
      #pragma unroll
      for (int q = 0; q < 4; ++q) {
        size_t base = ((size_t)(r0 + lq * 4 + q) * T_LEN + t) * HID;
        out[base + c0 + lr]      = acc0[q] + b0v;
        out[base + c0 + 16 + lr] = acc1[q] + b1v;
      }
    }
    __syncthreads();   // protect As before next granule's fill
  }
}

// ---- the 4-stage pipeline: 256 blocks = 64 B + 64 A + 64 C + 64 D ----
__global__ __launch_bounds__(NTHREADS)
void mega(const int* __restrict__ ids, const float* __restrict__ emb,
          const unsigned short* __restrict__ wbf, const float* __restrict__ db,
          unsigned short* __restrict__ xpT, unsigned short* __restrict__ hbuf,
          int* __restrict__ flags, float* __restrict__ out)
{
  __shared__ __align__(16) unsigned short smem[128 * HID];   // 64 KB
  const int role = blockIdx.x >> 6;
  const int bt   = blockIdx.x & 63;
  const int tid  = threadIdx.x;

  const unsigned short* Wih0 = wbf;
  const unsigned short* Whh0 = wbf + 1 * WSZ;
  const unsigned short* Wih1 = wbf + 2 * WSZ;
  const unsigned short* Whh1 = wbf + 3 * WSZ;
  const unsigned short* Wd   = wbf + 4 * WSZ;

  int* flagZ = flags + (0 * 64 + bt) * NGRAN;
  int* flagA = flags + (1 * 64 + bt) * NGRAN;
  int* flagB = flags + (2 * 64 + bt) * NGRAN;
  int* flagC = flags + (3 * 64 + bt) * NGRAN;

  if (role == 0) {
    role_b(ids, emb, Wih0, Wih1, xpT, hbuf, flagZ, flagA, flagB, smem, bt, tid);
  } else if (role == 1) {
    role_rec(xpT, Whh0, hbuf, flagZ, flagA, smem, bt, tid);
  } else if (role == 2) {
    role_rec(xpT, Whh1, hbuf, flagB, flagC, smem, bt, tid);
  } else {
    role_d(hbuf, Wd, db, out, flagC, smem, bt, tid);
  }
}

// ================= fallback (small ws): round-1 fused kernel ==========
__device__ __forceinline__ void layer_step(
    const bf16x8* ax, const bf16x8* ah,
    const unsigned short* __restrict__ Wih,
    const unsigned short* __restrict__ Whh,
    float (&hreg)[2][4],
    unsigned short* __restrict__ outb,
    int c0base, int lr, int lq)
{
  #pragma unroll
  for (int j = 0; j < 2; ++j) {
    const int c0 = c0base + j * 16;
    f32x4 xr = {0,0,0,0}, xz = {0,0,0,0}, xn = {0,0,0,0};
    f32x4 hr = {0,0,0,0}, hz = {0,0,0,0}, hn = {0,0,0,0};
    #pragma unroll
    for (int k = 0; k < 8; ++k) {
      const int kof = k * 32 + lq * 8;
      bf16x8 b0 = gw_frag(Wih,       c0 + lr, kof);
      bf16x8 b1 = gw_frag(Wih, 256 + c0 + lr, kof);
      bf16x8 b2 = gw_frag(Wih, 512 + c0 + lr, kof);
      bf16x8 w0 = gw_frag(Whh,       c0 + lr, kof);
      bf16x8 w1 = gw_frag(Whh, 256 + c0 + lr, kof);
      bf16x8 w2 = gw_frag(Whh, 512 + c0 + lr, kof);
      xr = __builtin_amdgcn_mfma_f32_16x16x32_bf16(ax[k], b0, xr, 0, 0, 0);
      xz = __builtin_amdgcn_mfma_f32_16x16x32_bf16(ax[k], b1, xz, 0, 0, 0);
      xn = __builtin_amdgcn_mfma_f32_16x16x32_bf16(ax[k], b2, xn, 0, 0, 0);
      hr = __builtin_amdgcn_mfma_f32_16x16x32_bf16(ah[k], w0, hr, 0, 0, 0);
      hz = __builtin_amdgcn_mfma_f32_16x16x32_bf16(ah[k], w1, hz, 0, 0, 0);
      hn = __builtin_amdgcn_mfma_f32_16x16x32_bf16(ah[k], w2, hn, 0, 0, 0);
    }
    #pragma unroll
    for (int q = 0; q < 4; ++q) {
      float r = sigm(xr[q] + hr[q]);
      float z = sigm(xz[q] + hz[q]);
      float n = tanh_f(xn[q] + r * hn[q]);
      float h = fmaf(z, hreg[j][q] - n, n);
      hreg[j][q] = h;
      int m = lq * 4 + q;
      int c = c0 + lr;
      int idx = m * HID + (((c >> 3) ^ (m & 7)) << 3) + (c & 7);
      outb[idx] = f2bf(h);
    }
  }
}

__global__ __launch_bounds__(NTHREADS)
void gru_fused(const int* __restrict__ ids,
               const float* __restrict__ emb,
               const unsigned short* __restrict__ wbf,
               const float* __restrict__ dense_b,
               float* __restrict__ out)
{
  __shared__ __align__(16) unsigned short x_bf[ROWS * HID];
  __shared__ __align__(16) unsigned short h0b[2][ROWS * HID];
  __shared__ __align__(16) unsigned short h1b[2][ROWS * HID];

  const int tid  = threadIdx.x;
  const int w    = tid >> 6;
  const int lane = tid & 63;
  const int lr   = lane & 15;
  const int lq   = lane >> 4;
  const int r0   = blockIdx.x * ROWS;
  const int c0base = w * 32;

  const unsigned short* Wih0 = wbf;
  const unsigned short* Whh0 = wbf + 1 * WSZ;
  const unsigned short* Wih1 = wbf + 2 * WSZ;
  const unsigned short* Whh1 = wbf + 3 * WSZ;
  const unsigned short* Wd   = wbf + 4 * WSZ;

  for (int i = tid; i < ROWS * HID; i += NTHREADS) {
    h0b[0][i] = 0; h0b[1][i] = 0; h1b[0][i] = 0; h1b[1][i] = 0;
  }
  float hreg0[2][4] = {}; float hreg1[2][4] = {};
  const float bias0 = dense_b[c0base + lr];
  const float bias1 = dense_b[c0base + 16 + lr];

  const int grow   = tid >> 5;
  const int gchunk = tid & 31;
  const int gswz   = grow * HID + ((gchunk ^ (grow & 7)) << 3);
  const int gid_base = (r0 + grow) * T_LEN;

  __syncthreads();

  int cur = 0;
  for (int t = 0; t < T_LEN; ++t) {
    {
      int rid = ids[gid_base + t];
      const f32x4* src = reinterpret_cast<const f32x4*>(emb + (size_t)rid * HID + gchunk * 8);
      f32x4 v0 = src[0];
      f32x4 v1 = src[1];
      uint4 pk;
      pk.x = (unsigned int)f2bf(v0[0]) | ((unsigned int)f2bf(v0[1]) << 16);
      pk.y = (unsigned int)f2bf(v0[2]) | ((unsigned int)f2bf(v0[3]) << 16);
      pk.z = (unsigned int)f2bf(v1[0]) | ((unsigned int)f2bf(v1[1]) << 16);
      pk.w = (unsigned int)f2bf(v1[2]) | ((unsigned int)f2bf(v1[3]) << 16);
      *reinterpret_cast<uint4*>(&x_bf[gswz]) = pk;
    }
    __syncthreads();

    bf16x8 ax[8], ah[8];
    #pragma unroll
    for (int k = 0; k < 8; ++k) {
      ax[k] = lds_frag(x_bf,     lr, k, lq);
      ah[k] = lds_frag(h0b[cur], lr, k, lq);
    }
    layer_step(ax, ah, Wih0, Whh0, hreg0, h0b[cur ^ 1], c0base, lr, lq);
    __syncthreads();

    #pragma unroll
    for (int k = 0; k < 8; ++k) {
      ax[k] = lds_frag(h0b[cur ^ 1], lr, k, lq);
      ah[k] = lds_frag(h1b[cur],     lr, k, lq);
    }
    layer_step(ax, ah, Wih1, Whh1, hreg1, h1b[cur ^ 1], c0base, lr, lq);
    __syncthreads();

    #pragma unroll
    for (int k = 0; k < 8; ++k) ax[k] = lds_frag(h1b[cur ^ 1], lr, k, lq);
    #pragma unroll
    for (int j = 0; j < 2; ++j) {
      const int c0 = c0base + j * 16;
      f32x4 acc = {0,0,0,0};
      #pragma unroll
      for (int k = 0; k < 8; ++k) {
        bf16x8 bw = gw_frag(Wd, c0 + lr, k * 32 + lq * 8);
        acc = __builtin_amdgcn_mfma_f32_16x16x32_bf16(ax[k], bw, acc, 0, 0, 0);
      }
      const float bias = j ? bias1 : bias0;
      size_t base = ((size_t)(r0 + lq * 4) * T_LEN + t) * HID + c0 + lr;
      #pragma unroll
      for (int q = 0; q < 4; ++q) {
        out[base + (size_t)q * T_LEN * HID] = acc[q] + bias;
      }
    }
    cur ^= 1;
  }
}

extern "C" void kernel_launch(void* const* d_in, const int* in_sizes, int n_in,
                              void* d_out, int out_size, void* d_ws, size_t ws_size,
                              hipStream_t stream) {
  const int*   ids  = (const int*)d_in[0];
  const float* emb  = (const float*)d_in[1];
  const float* wih0 = (const float*)d_in[2];
  const float* whh0 = (const float*)d_in[3];
  const float* wih1 = (const float*)d_in[4];
  const float* whh1 = (const float*)d_in[5];
  const float* dw   = (const float*)d_in[6];
  const float* db   = (const float*)d_in[7];

  unsigned short* wbf = (unsigned short*)d_ws;   // 1.7 MB of bf16 weights

  const int total = 4 * WSZ + HID * HID;
  convert_weights<<<(total + 255) / 256, 256, 0, stream>>>(wih0, whh0, wih1, whh1, dw, wbf);

  const size_t FLAGS_OFF  = 1835008;                              // 1.75 MB
  const size_t FLAG_BYTES = 4 * 64 * NGRAN * sizeof(int);         // 25.6 KB
  const size_t XP_OFF   = 2u * 1024u * 1024u;
  const size_t XP_BYTES = (size_t)T_LEN * G3 * BATCH * 2;         // 300 MB
  const size_t H_OFF    = XP_OFF + XP_BYTES;
  const size_t H_BYTES  = (size_t)BATCH * T_LEN * HID * 2;        // 100 MB
  const size_t NEED     = H_OFF + H_BYTES;                        // ~421.5 MB

  if (ws_size >= NEED) {
    unsigned short* xpT  = (unsigned short*)((char*)d_ws + XP_OFF);
    unsigned short* hbuf = (unsigned short*)((char*)d_ws + H_OFF);
    int* flags = (int*)((char*)d_ws + FLAGS_OFF);
    hipMemsetAsync(flags, 0, FLAG_BYTES, stream);
    mega<<<256, NTHREADS, 0, stream>>>(ids, emb, wbf, db, xpT, hbuf, flags, (float*)d_out);
  } else {
    gru_fused<<<64, NTHREADS, 0, stream>>>(ids, emb, wbf, db, (float*)d_out);
  }
}

// Round 15
// 3024.431 us; speedup vs baseline: 2.9962x; 2.9962x over previous
//
#include <hip/hip_runtime.h>

#define T_LEN 200
#define HID   256
#define BATCH 1024
#define G3    768
#define ROWS  16
#define NTHREADS 512
#define WSZ   196608   // 768*256 elements per GRU weight matrix

typedef __bf16  bf16x8 __attribute__((ext_vector_type(8)));
typedef float   f32x4  __attribute__((ext_vector_type(4)));

__device__ __forceinline__ unsigned short f2bf(float f) {
  union { float f; unsigned int u; } c; c.f = f;
  unsigned int u = c.u;
  u += 0x7FFFu + ((u >> 16) & 1u);     // round-to-nearest-even
  return (unsigned short)(u >> 16);
}
__device__ __forceinline__ float bf2f(unsigned int u16v) {
  union { unsigned int u; float f; } c; c.u = u16v << 16; return c.f;
}
__device__ __forceinline__ float sigm(float x) { return 1.0f / (1.0f + __expf(-x)); }
__device__ __forceinline__ float tanh_f(float x) { return 1.0f - 2.0f / (__expf(2.0f * x) + 1.0f); }

__global__ void convert_weights(const float* __restrict__ a,
                                const float* __restrict__ b,
                                const float* __restrict__ c,
                                const float* __restrict__ d,
                                const float* __restrict__ e,
                                unsigned short* __restrict__ out) {
  int i = blockIdx.x * blockDim.x + threadIdx.x;
  const int total = 4 * WSZ + HID * HID;
  if (i >= total) return;
  float v;
  if      (i < 1 * WSZ) v = a[i];
  else if (i < 2 * WSZ) v = b[i - 1 * WSZ];
  else if (i < 3 * WSZ) v = c[i - 2 * WSZ];
  else if (i < 4 * WSZ) v = d[i - 3 * WSZ];
  else                  v = e[i - 4 * WSZ];
  out[i] = f2bf(v);
}

__device__ __forceinline__ bf16x8 lds_frag(const unsigned short* buf, int row, int k, int lq) {
  int chunk = (k << 2) + lq;
  int idx = row * HID + ((chunk ^ (row & 7)) << 3);
  return *reinterpret_cast<const bf16x8*>(buf + idx);
}
__device__ __forceinline__ bf16x8 gw_frag(const unsigned short* __restrict__ W, int wrow, int kof) {
  return *reinterpret_cast<const bf16x8*>(W + (size_t)wrow * HID + kof);
}
__device__ __forceinline__ uint4 gw_fragu(const unsigned short* __restrict__ W, int wrow, int kof) {
  return *reinterpret_cast<const uint4*>(W + (size_t)wrow * HID + kof);
}
__device__ __forceinline__ bf16x8 as_bf(uint4 u) { return __builtin_bit_cast(bf16x8, u); }
__device__ __forceinline__ uint2 pack4(f32x4 v) {
  uint2 r;
  r.x = (unsigned int)f2bf(v[0]) | ((unsigned int)f2bf(v[1]) << 16);
  r.y = (unsigned int)f2bf(v[2]) | ((unsigned int)f2bf(v[3]) << 16);
  return r;
}

// xpT layout: [T][batch_tile(64)][G3][16 batch]  (24 KB contiguous per (t,bt))
// ================= phase 1 & 3: xp = A @ W^T ==========
template<int GATHER>
__global__ __launch_bounds__(NTHREADS)
void xp_gemm(const int* __restrict__ ids, const float* __restrict__ emb,
             const unsigned short* __restrict__ hsrc,
             const unsigned short* __restrict__ W,
             unsigned short* __restrict__ xpT)
{
  __shared__ __align__(16) unsigned short As[128 * HID];   // 64 KB
  const int tid = threadIdx.x;
  const int w = tid >> 6, lane = tid & 63, lr = lane & 15, lq = lane >> 4;
  const int bt = blockIdx.x & 63;          // batch tile
  const int tt = blockIdx.x >> 6;          // time tile 0..24
  const int r0 = bt * 16, t0 = tt * 8;

  for (int idx = tid; idx < 128 * 32; idx += NTHREADS) {
    int row = idx >> 5, cc = idx & 31;
    int bloc = row & 15, tloc = row >> 4;
    int sidx = row * HID + ((cc ^ (row & 7)) << 3);
    if (GATHER) {
      int rid = ids[(r0 + bloc) * T_LEN + t0 + tloc];
      const f32x4* src = reinterpret_cast<const f32x4*>(emb + (size_t)rid * HID + cc * 8);
      f32x4 v0 = src[0], v1 = src[1];
      uint4 pk;
      pk.x = (unsigned int)f2bf(v0[0]) | ((unsigned int)f2bf(v0[1]) << 16);
      pk.y = (unsigned int)f2bf(v0[2]) | ((unsigned int)f2bf(v0[3]) << 16);
      pk.z = (unsigned int)f2bf(v1[0]) | ((unsigned int)f2bf(v1[1]) << 16);
      pk.w = (unsigned int)f2bf(v1[2]) | ((unsigned int)f2bf(v1[3]) << 16);
      *reinterpret_cast<uint4*>(&As[sidx]) = pk;
    } else {
      uint4 v = *reinterpret_cast<const uint4*>(hsrc + ((size_t)(r0 + bloc) * T_LEN + t0 + tloc) * HID + cc * 8);
      *reinterpret_cast<uint4*>(&As[sidx]) = v;
    }
  }
  __syncthreads();

  const int colbase = w * 96;              // wave owns 96 cols (3 pairs of 16)
  #pragma unroll 1
  for (int mt = 0; mt < 8; ++mt) {
    bf16x8 a[8];
    #pragma unroll
    for (int k = 0; k < 8; ++k) a[k] = lds_frag(As, mt * 16 + lr, k, lq);
    const int t = t0 + mt;
    unsigned short* xprow = xpT + ((size_t)t * 64 + bt) * (G3 * 16);
    #pragma unroll
    for (int np = 0; np < 3; ++np) {
      const int c0 = colbase + np * 32;
      f32x4 acc0 = {0,0,0,0}, acc1 = {0,0,0,0};
      #pragma unroll
      for (int k = 0; k < 8; ++k) {
        const int kof = k * 32 + lq * 8;
        bf16x8 b0 = gw_frag(W, c0 + lr,      kof);
        bf16x8 b1 = gw_frag(W, c0 + 16 + lr, kof);
        acc0 = __builtin_amdgcn_mfma_f32_16x16x32_bf16(a[k], b0, acc0, 0, 0, 0);
        acc1 = __builtin_amdgcn_mfma_f32_16x16x32_bf16(a[k], b1, acc1, 0, 0, 0);
      }
      *reinterpret_cast<uint2*>(xprow + (c0 + lr)      * 16 + lq * 4) = pack4(acc0);
      *reinterpret_cast<uint2*>(xprow + (c0 + 16 + lr) * 16 + lq * 4) = pack4(acc1);
    }
  }
}

// ================= phase 2 & 4: recurrent GRU layer ==========
// R15: R11 verbatim except the xp prefetch is now TWO steps deep (pzA/pzB
// double-buffer, statically unrolled 2-step loop -- no runtime-indexed regs).
// Theory: rec is latency-bound on the 24KB/step xp stream (384 lines/step/CU,
// ~310 GB/s observed << BW ceiling). 1-deep prefetch serializes drain with
// compute; 2-deep doubles lines in flight -> step ~ max(compute, drain/2).
__global__ __launch_bounds__(NTHREADS)
__attribute__((amdgpu_waves_per_eu(2, 2)))
void gru_rec(const unsigned short* __restrict__ xpT,
             const unsigned short* __restrict__ Whh,
             unsigned short* __restrict__ hout)
{
  __shared__ __align__(16) unsigned short hb[2][ROWS * HID];   // 16 KB double buffer
  const int tid = threadIdx.x;
  const int w = tid >> 6, lane = tid & 63, lr = lane & 15, lq = lane >> 4;
  const int bt = blockIdx.x;
  const int r0 = bt * ROWS;
  const int c0 = w * 32;

  // Whh fragments for this wave's 32 cols x 3 gates: 192 dwords pinned to AGPR.
  uint4 wf[2][3][8];
  #pragma unroll
  for (int j = 0; j < 2; ++j)
    #pragma unroll
    for (int g = 0; g < 3; ++g)
      #pragma unroll
      for (int k = 0; k < 8; ++k)
        wf[j][g][k] = gw_fragu(Whh, g * 256 + c0 + j * 16 + lr, k * 32 + lq * 8);
  #pragma unroll
  for (int j = 0; j < 2; ++j)
    #pragma unroll
    for (int g = 0; g < 3; ++g)
      #pragma unroll
      for (int k = 0; k < 8; ++k)
        asm volatile("" : "+a"(wf[j][g][k].x), "+a"(wf[j][g][k].y),
                          "+a"(wf[j][g][k].z), "+a"(wf[j][g][k].w));

  for (int i = tid; i < ROWS * HID; i += NTHREADS) { hb[0][i] = 0; }

  f32x4 hreg[2] = {{0,0,0,0},{0,0,0,0}};

  const int bj0 = (c0 + lr) * 16 + lq * 4;

  const size_t slabstep = (size_t)64 * G3 * 16;
  const unsigned short* slab0 = xpT + (size_t)bt * (G3 * 16);

  __syncthreads();   // covers hb zero-init (one-time vmcnt drain is harmless)

  // preload steps 0 and 1
  uint2 pzA[2][3], pzB[2][3];
  #pragma unroll
  for (int g = 0; g < 3; ++g) {
    pzA[0][g] = *reinterpret_cast<const uint2*>(slab0 + g * 4096 + bj0);
    pzA[1][g] = *reinterpret_cast<const uint2*>(slab0 + g * 4096 + bj0 + 256);
  }
  {
    const unsigned short* s1 = slab0 + slabstep;
    #pragma unroll
    for (int g = 0; g < 3; ++g) {
      pzB[0][g] = *reinterpret_cast<const uint2*>(s1 + g * 4096 + bj0);
      pzB[1][g] = *reinterpret_cast<const uint2*>(s1 + g * 4096 + bj0 + 256);
    }
  }

  const unsigned short* slab_pre = slab0 + 2 * slabstep;   // prefetch target: t+2
  int tpre = 2;
  int t = 0;
  int cur = 0;

#define REC_STEP(PZ)                                                           \
  do {                                                                         \
    f32x4 acc[2][3];                                                           \
    uint2 xn0 = PZ[0][2], xn1 = PZ[1][2];                                      \
    _Pragma("unroll")                                                          \
    for (int j = 0; j < 2; ++j) {                                              \
      _Pragma("unroll")                                                        \
      for (int g = 0; g < 2; ++g) {                                            \
        uint2 p = PZ[j][g];                                                    \
        f32x4 v;                                                               \
        v[0] = bf2f(p.x & 0xffffu); v[1] = bf2f(p.x >> 16);                    \
        v[2] = bf2f(p.y & 0xffffu); v[3] = bf2f(p.y >> 16);                    \
        acc[j][g] = v;                                                         \
      }                                                                        \
      f32x4 z4 = {0,0,0,0};                                                    \
      acc[j][2] = z4;                                                          \
    }                                                                          \
    {                                                                          \
      const unsigned short* sp = (tpre < T_LEN) ? slab_pre                     \
                                                : slab_pre - 2 * slabstep;     \
      _Pragma("unroll")                                                        \
      for (int g = 0; g < 3; ++g) {                                            \
        PZ[0][g] = *reinterpret_cast<const uint2*>(sp + g * 4096 + bj0);       \
        PZ[1][g] = *reinterpret_cast<const uint2*>(sp + g * 4096 + bj0 + 256); \
      }                                                                        \
    }                                                                          \
    asm volatile("s_waitcnt lgkmcnt(0)\n\ts_barrier" ::: "memory");            \
    _Pragma("unroll")                                                          \
    for (int k = 0; k < 8; ++k) {                                              \
      bf16x8 a = lds_frag(hb[cur], lr, k, lq);                                 \
      _Pragma("unroll")                                                        \
      for (int j = 0; j < 2; ++j) {                                            \
        acc[j][0] = __builtin_amdgcn_mfma_f32_16x16x32_bf16(a, as_bf(wf[j][0][k]), acc[j][0], 0, 0, 0); \
        acc[j][1] = __builtin_amdgcn_mfma_f32_16x16x32_bf16(a, as_bf(wf[j][1][k]), acc[j][1], 0, 0, 0); \
        acc[j][2] = __builtin_amdgcn_mfma_f32_16x16x32_bf16(a, as_bf(wf[j][2][k]), acc[j][2], 0, 0, 0); \
      }                                                                        \
    }                                                                          \
    _Pragma("unroll")                                                          \
    for (int j = 0; j < 2; ++j) {                                              \
      uint2 xn = j ? xn1 : xn0;                                                \
      float xnv[4];                                                            \
      xnv[0] = bf2f(xn.x & 0xffffu); xnv[1] = bf2f(xn.x >> 16);                \
      xnv[2] = bf2f(xn.y & 0xffffu); xnv[3] = bf2f(xn.y >> 16);                \
      _Pragma("unroll")                                                        \
      for (int q = 0; q < 4; ++q) {                                            \
        float r = sigm(acc[j][0][q]);                                          \
        float z = sigm(acc[j][1][q]);                                          \
        float n = tanh_f(xnv[q] + r * acc[j][2][q]);                           \
        float hnew = fmaf(z, hreg[j][q] - n, n);                               \
        hreg[j][q] = hnew;                                                     \
        unsigned short hb16 = f2bf(hnew);                                      \
        int m = lq * 4 + q;                                                    \
        int c = c0 + j * 16 + lr;                                              \
        hb[cur ^ 1][m * HID + (((c >> 3) ^ (m & 7)) << 3) + (c & 7)] = hb16;   \
        hout[((size_t)(r0 + m) * T_LEN + t) * HID + c] = hb16;                 \
      }                                                                        \
    }                                                                          \
    slab_pre += slabstep; ++tpre; ++t; cur ^= 1;                               \
  } while (0)

  #pragma unroll 1
  for (int it = 0; it < T_LEN / 2; ++it) {
    REC_STEP(pzA);
    REC_STEP(pzB);
  }
#undef REC_STEP
}

// ================= phase 5: out = h1 @ Wd^T + b (fp32 out) ==========
__global__ __launch_bounds__(NTHREADS)
void dense_gemm(const unsigned short* __restrict__ hsrc,
                const unsigned short* __restrict__ Wd,
                const float* __restrict__ db,
                float* __restrict__ out)
{
  __shared__ __align__(16) unsigned short As[128 * HID];
  const int tid = threadIdx.x;
  const int w = tid >> 6, lane = tid & 63, lr = lane & 15, lq = lane >> 4;
  const int bt = blockIdx.x & 63;
  const int tt = blockIdx.x >> 6;
  const int r0 = bt * 16, t0 = tt * 8;

  for (int idx = tid; idx < 128 * 32; idx += NTHREADS) {
    int row = idx >> 5, cc = idx & 31;
    int bloc = row & 15, tloc = row >> 4;
    int sidx = row * HID + ((cc ^ (row & 7)) << 3);
    uint4 v = *reinterpret_cast<const uint4*>(hsrc + ((size_t)(r0 + bloc) * T_LEN + t0 + tloc) * HID + cc * 8);
    *reinterpret_cast<uint4*>(&As[sidx]) = v;
  }
  __syncthreads();

  const int c0 = w * 32;
  const float b0v = db[c0 + lr];
  const float b1v = db[c0 + 16 + lr];

  #pragma unroll 1
  for (int mt = 0; mt < 8; ++mt) {
    bf16x8 a[8];
    #pragma unroll
    for (int k = 0; k < 8; ++k) a[k] = lds_frag(As, mt * 16 + lr, k, lq);
    f32x4 acc0 = {0,0,0,0}, acc1 = {0,0,0,0};
    #pragma unroll
    for (int k = 0; k < 8; ++k) {
      const int kof = k * 32 + lq * 8;
      bf16x8 b0 = gw_frag(Wd, c0 + lr,      kof);
      bf16x8 b1 = gw_frag(Wd, c0 + 16 + lr, kof);
      acc0 = __builtin_amdgcn_mfma_f32_16x16x32_bf16(a[k], b0, acc0, 0, 0, 0);
      acc1 = __builtin_amdgcn_mfma_f32_16x16x32_bf16(a[k], b1, acc1, 0, 0, 0);
    }
    const int t = t0 + mt;
    #pragma unroll
    for (int q = 0; q < 4; ++q) {
      size_t base = ((size_t)(r0 + lq * 4 + q) * T_LEN + t) * HID;
      out[base + c0 + lr]      = acc0[q] + b0v;
      out[base + c0 + 16 + lr] = acc1[q] + b1v;
    }
  }
}

// ================= fallback (small ws): round-1 fused kernel ==========
__device__ __forceinline__ void layer_step(
    const bf16x8* ax, const bf16x8* ah,
    const unsigned short* __restrict__ Wih,
    const unsigned short* __restrict__ Whh,
    float (&hreg)[2][4],
    unsigned short* __restrict__ outb,
    int c0base, int lr, int lq)
{
  #pragma unroll
  for (int j = 0; j < 2; ++j) {
    const int c0 = c0base + j * 16;
    f32x4 xr = {0,0,0,0}, xz = {0,0,0,0}, xn = {0,0,0,0};
    f32x4 hr = {0,0,0,0}, hz = {0,0,0,0}, hn = {0,0,0,0};
    #pragma unroll
    for (int k = 0; k < 8; ++k) {
      const int kof = k * 32 + lq * 8;
      bf16x8 b0 = gw_frag(Wih,       c0 + lr, kof);
      bf16x8 b1 = gw_frag(Wih, 256 + c0 + lr, kof);
      bf16x8 b2 = gw_frag(Wih, 512 + c0 + lr, kof);
      bf16x8 w0 = gw_frag(Whh,       c0 + lr, kof);
      bf16x8 w1 = gw_frag(Whh, 256 + c0 + lr, kof);
      bf16x8 w2 = gw_frag(Whh, 512 + c0 + lr, kof);
      xr = __builtin_amdgcn_mfma_f32_16x16x32_bf16(ax[k], b0, xr, 0, 0, 0);
      xz = __builtin_amdgcn_mfma_f32_16x16x32_bf16(ax[k], b1, xz, 0, 0, 0);
      xn = __builtin_amdgcn_mfma_f32_16x16x32_bf16(ax[k], b2, xn, 0, 0, 0);
      hr = __builtin_amdgcn_mfma_f32_16x16x32_bf16(ah[k], w0, hr, 0, 0, 0);
      hz = __builtin_amdgcn_mfma_f32_16x16x32_bf16(ah[k], w1, hz, 0, 0, 0);
      hn = __builtin_amdgcn_mfma_f32_16x16x32_bf16(ah[k], w2, hn, 0, 0, 0);
    }
    #pragma unroll
    for (int q = 0; q < 4; ++q) {
      float r = sigm(xr[q] + hr[q]);
      float z = sigm(xz[q] + hz[q]);
      float n = tanh_f(xn[q] + r * hn[q]);
      float h = fmaf(z, hreg[j][q] - n, n);
      hreg[j][q] = h;
      int m = lq * 4 + q;
      int c = c0 + lr;
      int idx = m * HID + (((c >> 3) ^ (m & 7)) << 3) + (c & 7);
      outb[idx] = f2bf(h);
    }
  }
}

__global__ __launch_bounds__(NTHREADS)
void gru_fused(const int* __restrict__ ids,
               const float* __restrict__ emb,
               const unsigned short* __restrict__ wbf,
               const float* __restrict__ dense_b,
               float* __restrict__ out)
{
  __shared__ __align__(16) unsigned short x_bf[ROWS * HID];
  __shared__ __align__(16) unsigned short h0b[2][ROWS * HID];
  __shared__ __align__(16) unsigned short h1b[2][ROWS * HID];

  const int tid  = threadIdx.x;
  const int w    = tid >> 6;
  const int lane = tid & 63;
  const int lr   = lane & 15;
  const int lq   = lane >> 4;
  const int r0   = blockIdx.x * ROWS;
  const int c0base = w * 32;

  const unsigned short* Wih0 = wbf;
  const unsigned short* Whh0 = wbf + 1 * WSZ;
  const unsigned short* Wih1 = wbf + 2 * WSZ;
  const unsigned short* Whh1 = wbf + 3 * WSZ;
  const unsigned short* Wd   = wbf + 4 * WSZ;

  for (int i = tid; i < ROWS * HID; i += NTHREADS) {
    h0b[0][i] = 0; h0b[1][i] = 0; h1b[0][i] = 0; h1b[1][i] = 0;
  }
  float hreg0[2][4] = {}; float hreg1[2][4] = {};
  const float bias0 = dense_b[c0base + lr];
  const float bias1 = dense_b[c0base + 16 + lr];

  const int grow   = tid >> 5;
  const int gchunk = tid & 31;
  const int gswz   = grow * HID + ((gchunk ^ (grow & 7)) << 3);
  const int gid_base = (r0 + grow) * T_LEN;

  __syncthreads();

  int cur = 0;
  for (int t = 0; t < T_LEN; ++t) {
    {
      int rid = ids[gid_base + t];
      const f32x4* src = reinterpret_cast<const f32x4*>(emb + (size_t)rid * HID + gchunk * 8);
      f32x4 v0 = src[0];
      f32x4 v1 = src[1];
      uint4 pk;
      pk.x = (unsigned int)f2bf(v0[0]) | ((unsigned int)f2bf(v0[1]) << 16);
      pk.y = (unsigned int)f2bf(v0[2]) | ((unsigned int)f2bf(v0[3]) << 16);
      pk.z = (unsigned int)f2bf(v1[0]) | ((unsigned int)f2bf(v1[1]) << 16);
      pk.w = (unsigned int)f2bf(v1[2]) | ((unsigned int)f2bf(v1[3]) << 16);
      *reinterpret_cast<uint4*>(&x_bf[gswz]) = pk;
    }
    __syncthreads();

    bf16x8 ax[8], ah[8];
    #pragma unroll
    for (int k = 0; k < 8; ++k) {
      ax[k] = lds_frag(x_bf,     lr, k, lq);
      ah[k] = lds_frag(h0b[cur], lr, k, lq);
    }
    layer_step(ax, ah, Wih0, Whh0, hreg0, h0b[cur ^ 1], c0base, lr, lq);
    __syncthreads();

    #pragma unroll
    for (int k = 0; k < 8; ++k) {
      ax[k] = lds_frag(h0b[cur ^ 1], lr, k, lq);
      ah[k] = lds_frag(h1b[cur],     lr, k, lq);
    }
    layer_step(ax, ah, Wih1, Whh1, hreg1, h1b[cur ^ 1], c0base, lr, lq);
    __syncthreads();

    #pragma unroll
    for (int k = 0; k < 8; ++k) ax[k] = lds_frag(h1b[cur ^ 1], lr, k, lq);
    #pragma unroll
    for (int j = 0; j < 2; ++j) {
      const int c0 = c0base + j * 16;
      f32x4 acc = {0,0,0,0};
      #pragma unroll
      for (int k = 0; k < 8; ++k) {
        bf16x8 bw = gw_frag(Wd, c0 + lr, k * 32 + lq * 8);
        acc = __builtin_amdgcn_mfma_f32_16x16x32_bf16(ax[k], bw, acc, 0, 0, 0);
      }
      const float bias = j ? bias1 : bias0;
      size_t base = ((size_t)(r0 + lq * 4) * T_LEN + t) * HID + c0 + lr;
      #pragma unroll
      for (int q = 0; q < 4; ++q) {
        out[base + (size_t)q * T_LEN * HID] = acc[q] + bias;
      }
    }
    cur ^= 1;
  }
}

extern "C" void kernel_launch(void* const* d_in, const int* in_sizes, int n_in,
                              void* d_out, int out_size, void* d_ws, size_t ws_size,
                              hipStream_t stream) {
  const int*   ids  = (const int*)d_in[0];
  const float* emb  = (const float*)d_in[1];
  const float* wih0 = (const float*)d_in[2];
  const float* whh0 = (const float*)d_in[3];
  const float* wih1 = (const float*)d_in[4];
  const float* whh1 = (const float*)d_in[5];
  const float* dw   = (const float*)d_in[6];
  const float* db   = (const float*)d_in[7];

  unsigned short* wbf = (unsigned short*)d_ws;   // 851968 bf16 = 1.7 MB

  const int total = 4 * WSZ + HID * HID;
  convert_weights<<<(total + 255) / 256, 256, 0, stream>>>(wih0, whh0, wih1, whh1, dw, wbf);

  const size_t XP_OFF = 2u * 1024u * 1024u;
  const size_t XP_BYTES = (size_t)T_LEN * G3 * BATCH * 2;        // 314,572,800
  const size_t H_OFF  = XP_OFF + XP_BYTES;
  const size_t H_BYTES = (size_t)BATCH * T_LEN * HID * 2;        // 104,857,600
  const size_t NEED = H_OFF + H_BYTES;                           // ~421.5 MB

  if (ws_size >= NEED) {
    unsigned short* xpT  = (unsigned short*)((char*)d_ws + XP_OFF);
    unsigned short* hbuf = (unsigned short*)((char*)d_ws + H_OFF);
    const unsigned short* Wih0 = wbf;
    const unsigned short* Whh0 = wbf + 1 * WSZ;
    const unsigned short* Wih1 = wbf + 2 * WSZ;
    const unsigned short* Whh1 = wbf + 3 * WSZ;
    const unsigned short* Wd   = wbf + 4 * WSZ;

    xp_gemm<1><<<1600, NTHREADS, 0, stream>>>(ids, emb, nullptr, Wih0, xpT);
    gru_rec<<<64, NTHREADS, 0, stream>>>(xpT, Whh0, hbuf);
    xp_gemm<0><<<1600, NTHREADS, 0, stream>>>(nullptr, nullptr, hbuf, Wih1, xpT);
    gru_rec<<<64, NTHREADS, 0, stream>>>(xpT, Whh1, hbuf);
    dense_gemm<<<1600, NTHREADS, 0, stream>>>(hbuf, Wd, db, (float*)d_out);
  } else {
    gru_fused<<<64, NTHREADS, 0, stream>>>(ids, emb, wbf, db, (float*)d_out);
  }
}

// Round 16
// 2150.566 us; speedup vs baseline: 4.2136x; 1.4063x over previous
//
#include <hip/hip_runtime.h>

#define T_LEN 200
#define HID   256
#define BATCH 1024
#define G3    768
#define ROWS  16
#define NTHREADS 512
#define WSZ   196608   // 768*256 elements per GRU weight matrix

typedef __bf16  bf16x8 __attribute__((ext_vector_type(8)));
typedef float   f32x4  __attribute__((ext_vector_type(4)));

__device__ __forceinline__ unsigned short f2bf(float f) {
  union { float f; unsigned int u; } c; c.f = f;
  unsigned int u = c.u;
  u += 0x7FFFu + ((u >> 16) & 1u);     // round-to-nearest-even
  return (unsigned short)(u >> 16);
}
__device__ __forceinline__ float bf2f(unsigned int u16v) {
  union { unsigned int u; float f; } c; c.u = u16v << 16; return c.f;
}
__device__ __forceinline__ float sigm(float x) { return 1.0f / (1.0f + __expf(-x)); }
__device__ __forceinline__ float tanh_f(float x) { return 1.0f - 2.0f / (__expf(2.0f * x) + 1.0f); }

__global__ void convert_weights(const float* __restrict__ a,
                                const float* __restrict__ b,
                                const float* __restrict__ c,
                                const float* __restrict__ d,
                                const float* __restrict__ e,
                                unsigned short* __restrict__ out) {
  int i = blockIdx.x * blockDim.x + threadIdx.x;
  const int total = 4 * WSZ + HID * HID;
  if (i >= total) return;
  float v;
  if      (i < 1 * WSZ) v = a[i];
  else if (i < 2 * WSZ) v = b[i - 1 * WSZ];
  else if (i < 3 * WSZ) v = c[i - 2 * WSZ];
  else if (i < 4 * WSZ) v = d[i - 3 * WSZ];
  else                  v = e[i - 4 * WSZ];
  out[i] = f2bf(v);
}

__device__ __forceinline__ bf16x8 lds_frag(const unsigned short* buf, int row, int k, int lq) {
  int chunk = (k << 2) + lq;
  int idx = row * HID + ((chunk ^ (row & 7)) << 3);
  return *reinterpret_cast<const bf16x8*>(buf + idx);
}
__device__ __forceinline__ bf16x8 gw_frag(const unsigned short* __restrict__ W, int wrow, int kof) {
  return *reinterpret_cast<const bf16x8*>(W + (size_t)wrow * HID + kof);
}
__device__ __forceinline__ uint4 gw_fragu(const unsigned short* __restrict__ W, int wrow, int kof) {
  return *reinterpret_cast<const uint4*>(W + (size_t)wrow * HID + kof);
}
__device__ __forceinline__ bf16x8 as_bf(uint4 u) { return __builtin_bit_cast(bf16x8, u); }
__device__ __forceinline__ uint2 pack4(f32x4 v) {
  uint2 r;
  r.x = (unsigned int)f2bf(v[0]) | ((unsigned int)f2bf(v[1]) << 16);
  r.y = (unsigned int)f2bf(v[2]) | ((unsigned int)f2bf(v[3]) << 16);
  return r;
}

// xpT layout: [T][batch_tile(64)][G3][16 batch]  (24 KB contiguous per (t,bt))
// ================= phase 1 & 3: xp = A @ W^T ==========
template<int GATHER>
__global__ __launch_bounds__(NTHREADS)
void xp_gemm(const int* __restrict__ ids, const float* __restrict__ emb,
             const unsigned short* __restrict__ hsrc,
             const unsigned short* __restrict__ W,
             unsigned short* __restrict__ xpT)
{
  __shared__ __align__(16) unsigned short As[128 * HID];   // 64 KB
  const int tid = threadIdx.x;
  const int w = tid >> 6, lane = tid & 63, lr = lane & 15, lq = lane >> 4;
  const int bt = blockIdx.x & 63;          // batch tile
  const int tt = blockIdx.x >> 6;          // time tile 0..24
  const int r0 = bt * 16, t0 = tt * 8;

  for (int idx = tid; idx < 128 * 32; idx += NTHREADS) {
    int row = idx >> 5, cc = idx & 31;
    int bloc = row & 15, tloc = row >> 4;
    int sidx = row * HID + ((cc ^ (row & 7)) << 3);
    if (GATHER) {
      int rid = ids[(r0 + bloc) * T_LEN + t0 + tloc];
      const f32x4* src = reinterpret_cast<const f32x4*>(emb + (size_t)rid * HID + cc * 8);
      f32x4 v0 = src[0], v1 = src[1];
      uint4 pk;
      pk.x = (unsigned int)f2bf(v0[0]) | ((unsigned int)f2bf(v0[1]) << 16);
      pk.y = (unsigned int)f2bf(v0[2]) | ((unsigned int)f2bf(v0[3]) << 16);
      pk.z = (unsigned int)f2bf(v1[0]) | ((unsigned int)f2bf(v1[1]) << 16);
      pk.w = (unsigned int)f2bf(v1[2]) | ((unsigned int)f2bf(v1[3]) << 16);
      *reinterpret_cast<uint4*>(&As[sidx]) = pk;
    } else {
      uint4 v = *reinterpret_cast<const uint4*>(hsrc + ((size_t)(r0 + bloc) * T_LEN + t0 + tloc) * HID + cc * 8);
      *reinterpret_cast<uint4*>(&As[sidx]) = v;
    }
  }
  __syncthreads();

  const int colbase = w * 96;              // wave owns 96 cols (3 pairs of 16)
  #pragma unroll 1
  for (int mt = 0; mt < 8; ++mt) {
    bf16x8 a[8];
    #pragma unroll
    for (int k = 0; k < 8; ++k) a[k] = lds_frag(As, mt * 16 + lr, k, lq);
    const int t = t0 + mt;
    unsigned short* xprow = xpT + ((size_t)t * 64 + bt) * (G3 * 16);
    #pragma unroll
    for (int np = 0; np < 3; ++np) {
      const int c0 = colbase + np * 32;
      f32x4 acc0 = {0,0,0,0}, acc1 = {0,0,0,0};
      #pragma unroll
      for (int k = 0; k < 8; ++k) {
        const int kof = k * 32 + lq * 8;
        bf16x8 b0 = gw_frag(W, c0 + lr,      kof);
        bf16x8 b1 = gw_frag(W, c0 + 16 + lr, kof);
        acc0 = __builtin_amdgcn_mfma_f32_16x16x32_bf16(a[k], b0, acc0, 0, 0, 0);
        acc1 = __builtin_amdgcn_mfma_f32_16x16x32_bf16(a[k], b1, acc1, 0, 0, 0);
      }
      *reinterpret_cast<uint2*>(xprow + (c0 + lr)      * 16 + lq * 4) = pack4(acc0);
      *reinterpret_cast<uint2*>(xprow + (c0 + 16 + lr) * 16 + lq * 4) = pack4(acc1);
    }
  }
}

// ================= phase 2 & 4: recurrent GRU layer ==========
// R16 = exact revert to R11, the empirical optimum (rec 871us). All axes
// falsified over R4-R15: weight residency +/-5%, store pattern -13%, wave
// shape -20%, VALU cuts -16%, cross-stage pipeline -4x, 2-deep prefetch -50%
// (spills: WRITE_SIZE 106->143MB). The ~4.4us/step floor is structural for a
// 200-iteration serial chain on 64 CUs.
__global__ __launch_bounds__(NTHREADS)
__attribute__((amdgpu_waves_per_eu(2, 2)))
void gru_rec(const unsigned short* __restrict__ xpT,
             const unsigned short* __restrict__ Whh,
             unsigned short* __restrict__ hout)
{
  __shared__ __align__(16) unsigned short hb[2][ROWS * HID];   // 16 KB double buffer
  const int tid = threadIdx.x;
  const int w = tid >> 6, lane = tid & 63, lr = lane & 15, lq = lane >> 4;
  const int bt = blockIdx.x;
  const int r0 = bt * ROWS;
  const int c0 = w * 32;

  // Whh fragments for this wave's 32 cols x 3 gates: 192 dwords pinned to AGPR.
  uint4 wf[2][3][8];
  #pragma unroll
  for (int j = 0; j < 2; ++j)
    #pragma unroll
    for (int g = 0; g < 3; ++g)
      #pragma unroll
      for (int k = 0; k < 8; ++k)
        wf[j][g][k] = gw_fragu(Whh, g * 256 + c0 + j * 16 + lr, k * 32 + lq * 8);
  #pragma unroll
  for (int j = 0; j < 2; ++j)
    #pragma unroll
    for (int g = 0; g < 3; ++g)
      #pragma unroll
      for (int k = 0; k < 8; ++k)
        asm volatile("" : "+a"(wf[j][g][k].x), "+a"(wf[j][g][k].y),
                          "+a"(wf[j][g][k].z), "+a"(wf[j][g][k].w));

  for (int i = tid; i < ROWS * HID; i += NTHREADS) { hb[0][i] = 0; }

  f32x4 hreg[2] = {{0,0,0,0},{0,0,0,0}};

  const int bj0 = (c0 + lr) * 16 + lq * 4;

  const size_t slabstep = (size_t)64 * G3 * 16;
  const unsigned short* slab = xpT + (size_t)bt * (G3 * 16);

  __syncthreads();   // covers hb zero-init (one-time vmcnt drain is harmless)

  // prefetch all gates for t=0
  uint2 pz[2][3];
  #pragma unroll
  for (int g = 0; g < 3; ++g) {
    pz[0][g] = *reinterpret_cast<const uint2*>(slab + g * 4096 + bj0);
    pz[1][g] = *reinterpret_cast<const uint2*>(slab + g * 4096 + bj0 + 256);
  }

  int cur = 0;
  #pragma unroll 1
  for (int t = 0; t < T_LEN; ++t) {
    // consume prefetched xp: seed r,z accumulators; keep xn packed in regs
    f32x4 acc[2][3];
    uint2 xn0 = pz[0][2], xn1 = pz[1][2];
    #pragma unroll
    for (int j = 0; j < 2; ++j) {
      #pragma unroll
      for (int g = 0; g < 2; ++g) {
        uint2 p = pz[j][g];
        f32x4 v;
        v[0] = bf2f(p.x & 0xffffu); v[1] = bf2f(p.x >> 16);
        v[2] = bf2f(p.y & 0xffffu); v[3] = bf2f(p.y >> 16);
        acc[j][g] = v;
      }
      f32x4 z4 = {0,0,0,0};
      acc[j][2] = z4;
    }

    // prefetch next step (barrier below does NOT drain vmcnt)
    {
      const unsigned short* slab2 = (t + 1 < T_LEN) ? slab + slabstep : slab;
      #pragma unroll
      for (int g = 0; g < 3; ++g) {
        pz[0][g] = *reinterpret_cast<const uint2*>(slab2 + g * 4096 + bj0);
        pz[1][g] = *reinterpret_cast<const uint2*>(slab2 + g * 4096 + bj0 + 256);
      }
    }

    // LDS-only barrier: wait own ds ops, then s_barrier. No vmcnt(0) drain.
    asm volatile("s_waitcnt lgkmcnt(0)\n\ts_barrier" ::: "memory");

    #pragma unroll
    for (int k = 0; k < 8; ++k) {
      bf16x8 a = lds_frag(hb[cur], lr, k, lq);
      #pragma unroll
      for (int j = 0; j < 2; ++j) {
        acc[j][0] = __builtin_amdgcn_mfma_f32_16x16x32_bf16(a, as_bf(wf[j][0][k]), acc[j][0], 0, 0, 0);
        acc[j][1] = __builtin_amdgcn_mfma_f32_16x16x32_bf16(a, as_bf(wf[j][1][k]), acc[j][1], 0, 0, 0);
        acc[j][2] = __builtin_amdgcn_mfma_f32_16x16x32_bf16(a, as_bf(wf[j][2][k]), acc[j][2], 0, 0, 0);
      }
    }

    #pragma unroll
    for (int j = 0; j < 2; ++j) {
      uint2 xn = j ? xn1 : xn0;
      float xnv[4];
      xnv[0] = bf2f(xn.x & 0xffffu); xnv[1] = bf2f(xn.x >> 16);
      xnv[2] = bf2f(xn.y & 0xffffu); xnv[3] = bf2f(xn.y >> 16);
      #pragma unroll
      for (int q = 0; q < 4; ++q) {
        float r = sigm(acc[j][0][q]);
        float z = sigm(acc[j][1][q]);
        float n = tanh_f(xnv[q] + r * acc[j][2][q]);
        float hnew = fmaf(z, hreg[j][q] - n, n);   // (1-z)*n + z*h
        hreg[j][q] = hnew;
        unsigned short hb16 = f2bf(hnew);
        int m = lq * 4 + q;
        int c = c0 + j * 16 + lr;
        hb[cur ^ 1][m * HID + (((c >> 3) ^ (m & 7)) << 3) + (c & 7)] = hb16;
        hout[((size_t)(r0 + m) * T_LEN + t) * HID + c] = hb16;
      }
    }
    slab += slabstep;
    cur ^= 1;
  }
}

// ================= phase 5: out = h1 @ Wd^T + b (fp32 out) ==========
__global__ __launch_bounds__(NTHREADS)
void dense_gemm(const unsigned short* __restrict__ hsrc,
                const unsigned short* __restrict__ Wd,
                const float* __restrict__ db,
                float* __restrict__ out)
{
  __shared__ __align__(16) unsigned short As[128 * HID];
  const int tid = threadIdx.x;
  const int w = tid >> 6, lane = tid & 63, lr = lane & 15, lq = lane >> 4;
  const int bt = blockIdx.x & 63;
  const int tt = blockIdx.x >> 6;
  const int r0 = bt * 16, t0 = tt * 8;

  for (int idx = tid; idx < 128 * 32; idx += NTHREADS) {
    int row = idx >> 5, cc = idx & 31;
    int bloc = row & 15, tloc = row >> 4;
    int sidx = row * HID + ((cc ^ (row & 7)) << 3);
    uint4 v = *reinterpret_cast<const uint4*>(hsrc + ((size_t)(r0 + bloc) * T_LEN + t0 + tloc) * HID + cc * 8);
    *reinterpret_cast<uint4*>(&As[sidx]) = v;
  }
  __syncthreads();

  const int c0 = w * 32;
  const float b0v = db[c0 + lr];
  const float b1v = db[c0 + 16 + lr];

  #pragma unroll 1
  for (int mt = 0; mt < 8; ++mt) {
    bf16x8 a[8];
    #pragma unroll
    for (int k = 0; k < 8; ++k) a[k] = lds_frag(As, mt * 16 + lr, k, lq);
    f32x4 acc0 = {0,0,0,0}, acc1 = {0,0,0,0};
    #pragma unroll
    for (int k = 0; k < 8; ++k) {
      const int kof = k * 32 + lq * 8;
      bf16x8 b0 = gw_frag(Wd, c0 + lr,      kof);
      bf16x8 b1 = gw_frag(Wd, c0 + 16 + lr, kof);
      acc0 = __builtin_amdgcn_mfma_f32_16x16x32_bf16(a[k], b0, acc0, 0, 0, 0);
      acc1 = __builtin_amdgcn_mfma_f32_16x16x32_bf16(a[k], b1, acc1, 0, 0, 0);
    }
    const int t = t0 + mt;
    #pragma unroll
    for (int q = 0; q < 4; ++q) {
      size_t base = ((size_t)(r0 + lq * 4 + q) * T_LEN + t) * HID;
      out[base + c0 + lr]      = acc0[q] + b0v;
      out[base + c0 + 16 + lr] = acc1[q] + b1v;
    }
  }
}

// ================= fallback (small ws): round-1 fused kernel ==========
__device__ __forceinline__ void layer_step(
    const bf16x8* ax, const bf16x8* ah,
    const unsigned short* __restrict__ Wih,
    const unsigned short* __restrict__ Whh,
    float (&hreg)[2][4],
    unsigned short* __restrict__ outb,
    int c0base, int lr, int lq)
{
  #pragma unroll
  for (int j = 0; j < 2; ++j) {
    const int c0 = c0base + j * 16;
    f32x4 xr = {0,0,0,0}, xz = {0,0,0,0}, xn = {0,0,0,0};
    f32x4 hr = {0,0,0,0}, hz = {0,0,0,0}, hn = {0,0,0,0};
    #pragma unroll
    for (int k = 0; k < 8; ++k) {
      const int kof = k * 32 + lq * 8;
      bf16x8 b0 = gw_frag(Wih,       c0 + lr, kof);
      bf16x8 b1 = gw_frag(Wih, 256 + c0 + lr, kof);
      bf16x8 b2 = gw_frag(Wih, 512 + c0 + lr, kof);
      bf16x8 w0 = gw_frag(Whh,       c0 + lr, kof);
      bf16x8 w1 = gw_frag(Whh, 256 + c0 + lr, kof);
      bf16x8 w2 = gw_frag(Whh, 512 + c0 + lr, kof);
      xr = __builtin_amdgcn_mfma_f32_16x16x32_bf16(ax[k], b0, xr, 0, 0, 0);
      xz = __builtin_amdgcn_mfma_f32_16x16x32_bf16(ax[k], b1, xz, 0, 0, 0);
      xn = __builtin_amdgcn_mfma_f32_16x16x32_bf16(ax[k], b2, xn, 0, 0, 0);
      hr = __builtin_amdgcn_mfma_f32_16x16x32_bf16(ah[k], w0, hr, 0, 0, 0);
      hz = __builtin_amdgcn_mfma_f32_16x16x32_bf16(ah[k], w1, hz, 0, 0, 0);
      hn = __builtin_amdgcn_mfma_f32_16x16x32_bf16(ah[k], w2, hn, 0, 0, 0);
    }
    #pragma unroll
    for (int q = 0; q < 4; ++q) {
      float r = sigm(xr[q] + hr[q]);
      float z = sigm(xz[q] + hz[q]);
      float n = tanh_f(xn[q] + r * hn[q]);
      float h = fmaf(z, hreg[j][q] - n, n);
      hreg[j][q] = h;
      int m = lq * 4 + q;
      int c = c0 + lr;
      int idx = m * HID + (((c >> 3) ^ (m & 7)) << 3) + (c & 7);
      outb[idx] = f2bf(h);
    }
  }
}

__global__ __launch_bounds__(NTHREADS)
void gru_fused(const int* __restrict__ ids,
               const float* __restrict__ emb,
               const unsigned short* __restrict__ wbf,
               const float* __restrict__ dense_b,
               float* __restrict__ out)
{
  __shared__ __align__(16) unsigned short x_bf[ROWS * HID];
  __shared__ __align__(16) unsigned short h0b[2][ROWS * HID];
  __shared__ __align__(16) unsigned short h1b[2][ROWS * HID];

  const int tid  = threadIdx.x;
  const int w    = tid >> 6;
  const int lane = tid & 63;
  const int lr   = lane & 15;
  const int lq   = lane >> 4;
  const int r0   = blockIdx.x * ROWS;
  const int c0base = w * 32;

  const unsigned short* Wih0 = wbf;
  const unsigned short* Whh0 = wbf + 1 * WSZ;
  const unsigned short* Wih1 = wbf + 2 * WSZ;
  const unsigned short* Whh1 = wbf + 3 * WSZ;
  const unsigned short* Wd   = wbf + 4 * WSZ;

  for (int i = tid; i < ROWS * HID; i += NTHREADS) {
    h0b[0][i] = 0; h0b[1][i] = 0; h1b[0][i] = 0; h1b[1][i] = 0;
  }
  float hreg0[2][4] = {}; float hreg1[2][4] = {};
  const float bias0 = dense_b[c0base + lr];
  const float bias1 = dense_b[c0base + 16 + lr];

  const int grow   = tid >> 5;
  const int gchunk = tid & 31;
  const int gswz   = grow * HID + ((gchunk ^ (grow & 7)) << 3);
  const int gid_base = (r0 + grow) * T_LEN;

  __syncthreads();

  int cur = 0;
  for (int t = 0; t < T_LEN; ++t) {
    {
      int rid = ids[gid_base + t];
      const f32x4* src = reinterpret_cast<const f32x4*>(emb + (size_t)rid * HID + gchunk * 8);
      f32x4 v0 = src[0];
      f32x4 v1 = src[1];
      uint4 pk;
      pk.x = (unsigned int)f2bf(v0[0]) | ((unsigned int)f2bf(v0[1]) << 16);
      pk.y = (unsigned int)f2bf(v0[2]) | ((unsigned int)f2bf(v0[3]) << 16);
      pk.z = (unsigned int)f2bf(v1[0]) | ((unsigned int)f2bf(v1[1]) << 16);
      pk.w = (unsigned int)f2bf(v1[2]) | ((unsigned int)f2bf(v1[3]) << 16);
      *reinterpret_cast<uint4*>(&x_bf[gswz]) = pk;
    }
    __syncthreads();

    bf16x8 ax[8], ah[8];
    #pragma unroll
    for (int k = 0; k < 8; ++k) {
      ax[k] = lds_frag(x_bf,     lr, k, lq);
      ah[k] = lds_frag(h0b[cur], lr, k, lq);
    }
    layer_step(ax, ah, Wih0, Whh0, hreg0, h0b[cur ^ 1], c0base, lr, lq);
    __syncthreads();

    #pragma unroll
    for (int k = 0; k < 8; ++k) {
      ax[k] = lds_frag(h0b[cur ^ 1], lr, k, lq);
      ah[k] = lds_frag(h1b[cur],     lr, k, lq);
    }
    layer_step(ax, ah, Wih1, Whh1, hreg1, h1b[cur ^ 1], c0base, lr, lq);
    __syncthreads();

    #pragma unroll
    for (int k = 0; k < 8; ++k) ax[k] = lds_frag(h1b[cur ^ 1], lr, k, lq);
    #pragma unroll
    for (int j = 0; j < 2; ++j) {
      const int c0 = c0base + j * 16;
      f32x4 acc = {0,0,0,0};
      #pragma unroll
      for (int k = 0; k < 8; ++k) {
        bf16x8 bw = gw_frag(Wd, c0 + lr, k * 32 + lq * 8);
        acc = __builtin_amdgcn_mfma_f32_16x16x32_bf16(ax[k], bw, acc, 0, 0, 0);
      }
      const float bias = j ? bias1 : bias0;
      size_t base = ((size_t)(r0 + lq * 4) * T_LEN + t) * HID + c0 + lr;
      #pragma unroll
      for (int q = 0; q < 4; ++q) {
        out[base + (size_t)q * T_LEN * HID] = acc[q] + bias;
      }
    }
    cur ^= 1;
  }
}

extern "C" void kernel_launch(void* const* d_in, const int* in_sizes, int n_in,
                              void* d_out, int out_size, void* d_ws, size_t ws_size,
                              hipStream_t stream) {
  const int*   ids  = (const int*)d_in[0];
  const float* emb  = (const float*)d_in[1];
  const float* wih0 = (const float*)d_in[2];
  const float* whh0 = (const float*)d_in[3];
  const float* wih1 = (const float*)d_in[4];
  const float* whh1 = (const float*)d_in[5];
  const float* dw   = (const float*)d_in[6];
  const float* db   = (const float*)d_in[7];

  unsigned short* wbf = (unsigned short*)d_ws;   // 851968 bf16 = 1.7 MB

  const int total = 4 * WSZ + HID * HID;
  convert_weights<<<(total + 255) / 256, 256, 0, stream>>>(wih0, whh0, wih1, whh1, dw, wbf);

  const size_t XP_OFF = 2u * 1024u * 1024u;
  const size_t XP_BYTES = (size_t)T_LEN * G3 * BATCH * 2;        // 314,572,800
  const size_t H_OFF  = XP_OFF + XP_BYTES;
  const size_t H_BYTES = (size_t)BATCH * T_LEN * HID * 2;        // 104,857,600
  const size_t NEED = H_OFF + H_BYTES;                           // ~421.5 MB

  if (ws_size >= NEED) {
    unsigned short* xpT  = (unsigned short*)((char*)d_ws + XP_OFF);
    unsigned short* hbuf = (unsigned short*)((char*)d_ws + H_OFF);
    const unsigned short* Wih0 = wbf;
    const unsigned short* Whh0 = wbf + 1 * WSZ;
    const unsigned short* Wih1 = wbf + 2 * WSZ;
    const unsigned short* Whh1 = wbf + 3 * WSZ;
    const unsigned short* Wd   = wbf + 4 * WSZ;

    xp_gemm<1><<<1600, NTHREADS, 0, stream>>>(ids, emb, nullptr, Wih0, xpT);
    gru_rec<<<64, NTHREADS, 0, stream>>>(xpT, Whh0, hbuf);
    xp_gemm<0><<<1600, NTHREADS, 0, stream>>>(nullptr, nullptr, hbuf, Wih1, xpT);
    gru_rec<<<64, NTHREADS, 0, stream>>>(xpT, Whh1, hbuf);
    dense_gemm<<<1600, NTHREADS, 0, stream>>>(hbuf, Wd, db, (float*)d_out);
  } else {
    gru_fused<<<64, NTHREADS, 0, stream>>>(ids, emb, wbf, db, (float*)d_out);
  }
}